// Round 1
// baseline (308.759 us; speedup 1.0000x reference)
//
#include <hip/hip_runtime.h>
#include <hip/hip_bf16.h>

#define B_ 32
#define T_ 512
#define D_ 512
#define MAXF_ 4096

// Stage 1: per-batch inclusive scan of durations -> ends[b][t]; mel_lens -> out tail (as float)
__global__ __launch_bounds__(512) void lr_scan_kernel(const int* __restrict__ dur,
                                                      int* __restrict__ ends,
                                                      float* __restrict__ mel_out) {
    __shared__ int s[T_];
    const int b = blockIdx.x;
    const int t = threadIdx.x;
    s[t] = dur[b * T_ + t];
    __syncthreads();
    #pragma unroll
    for (int off = 1; off < T_; off <<= 1) {
        int tmp = (t >= off) ? s[t - off] : 0;
        __syncthreads();
        s[t] += tmp;
        __syncthreads();
    }
    ends[b * T_ + t] = s[t];
    if (t == T_ - 1) {
        int total = s[T_ - 1];
        mel_out[b] = (float)(total > 1 ? total : 1);
    }
}

// Stage 2: block = (128,2). Each y-slice handles one output frame p; 128 lanes x float4 = 512 floats.
__global__ __launch_bounds__(256) void lr_gather_kernel(const float* __restrict__ x,
                                                        const int* __restrict__ ends,
                                                        float* __restrict__ out) {
    __shared__ int s_ends[T_];
    const int b = blockIdx.y;
    const int* eb = ends + b * T_;
    for (int i = threadIdx.y * 128 + threadIdx.x; i < T_; i += 256)
        s_ends[i] = eb[i];
    __syncthreads();

    const int total = s_ends[T_ - 1];
    const int p = blockIdx.x * 2 + threadIdx.y;
    const int tx = threadIdx.x;

    float4* orow = (float4*)(out + ((size_t)b * MAXF_ + p) * D_);
    if (p >= total) {
        orow[tx] = make_float4(0.f, 0.f, 0.f, 0.f);
    } else {
        // first index i with s_ends[i] > p (guaranteed to exist since p < total)
        int lo = 0, hi = T_;
        while (lo < hi) {
            int mid = (lo + hi) >> 1;
            if (s_ends[mid] <= p) lo = mid + 1;
            else hi = mid;
        }
        int idx = lo < (T_ - 1) ? lo : (T_ - 1);
        const float4* xrow = (const float4*)(x + ((size_t)b * T_ + idx) * D_);
        orow[tx] = xrow[tx];
    }
}

extern "C" void kernel_launch(void* const* d_in, const int* in_sizes, int n_in,
                              void* d_out, int out_size, void* d_ws, size_t ws_size,
                              hipStream_t stream) {
    const float* x = (const float*)d_in[0];
    const int* durations = (const int*)d_in[1];
    float* out = (float*)d_out;
    float* mel_out = out + (size_t)B_ * MAXF_ * D_;
    int* ends = (int*)d_ws;  // B_*T_ ints = 64 KB

    lr_scan_kernel<<<B_, T_, 0, stream>>>(durations, ends, mel_out);

    dim3 grid(MAXF_ / 2, B_);
    dim3 block(128, 2);
    lr_gather_kernel<<<grid, block, 0, stream>>>(x, ends, out);
}

// Round 2
// 306.412 us; speedup vs baseline: 1.0077x; 1.0077x over previous
//
#include <hip/hip_runtime.h>
#include <hip/hip_bf16.h>

#define B_ 32
#define T_ 512
#define D_ 512
#define MAXF_ 4096

// Stage 1: per-batch scan of durations in LDS, write mel_lens, and precompute
// the frame->source-row map (idx_map, -1 for masked frames). 32 blocks x 512.
__global__ __launch_bounds__(512) void lr_scan_idx_kernel(const int* __restrict__ dur,
                                                          int* __restrict__ idx_map,
                                                          float* __restrict__ mel_out) {
    __shared__ int s[T_];
    const int b = blockIdx.x;
    const int t = threadIdx.x;
    s[t] = dur[b * T_ + t];
    __syncthreads();
    #pragma unroll
    for (int off = 1; off < T_; off <<= 1) {
        int tmp = (t >= off) ? s[t - off] : 0;
        __syncthreads();
        s[t] += tmp;
        __syncthreads();
    }
    const int total = s[T_ - 1];
    if (t == T_ - 1) {
        mel_out[b] = (float)(total > 1 ? total : 1);
    }
    // 8 frames per thread: binary search in LDS (broadcast-friendly, off hot path)
    for (int p = t; p < MAXF_; p += T_) {
        int v = -1;
        if (p < total) {
            int lo = 0, hi = T_;
            while (lo < hi) {
                int mid = (lo + hi) >> 1;
                if (s[mid] <= p) lo = mid + 1;
                else hi = mid;
            }
            v = lo < (T_ - 1) ? lo : (T_ - 1);
        }
        idx_map[b * MAXF_ + p] = v;
    }
}

// Stage 2: pure streaming gather. One thread per output float4.
// 128 consecutive lanes share one frame -> idx load broadcasts, then
// coalesced float4 read + float4 write. No LDS, no barriers.
__global__ __launch_bounds__(256) void lr_gather_kernel(const float4* __restrict__ x,
                                                        const int* __restrict__ idx_map,
                                                        float4* __restrict__ out) {
    const size_t gid = (size_t)blockIdx.x * 256 + threadIdx.x;
    const int frame = (int)(gid >> 7);   // b*MAXF_ + p
    const int c = (int)(gid & 127);
    const int idx = idx_map[frame];
    float4 v;
    if (idx < 0) {
        v = make_float4(0.f, 0.f, 0.f, 0.f);
    } else {
        const int b = frame >> 12;       // MAXF_ = 4096
        v = x[((size_t)(b * T_ + idx) << 7) + c];
    }
    out[gid] = v;
}

extern "C" void kernel_launch(void* const* d_in, const int* in_sizes, int n_in,
                              void* d_out, int out_size, void* d_ws, size_t ws_size,
                              hipStream_t stream) {
    const float* x = (const float*)d_in[0];
    const int* durations = (const int*)d_in[1];
    float* out = (float*)d_out;
    float* mel_out = out + (size_t)B_ * MAXF_ * D_;
    int* idx_map = (int*)d_ws;  // B_*MAXF_ ints = 512 KB

    lr_scan_idx_kernel<<<B_, T_, 0, stream>>>(durations, idx_map, mel_out);

    const size_t n_vec4 = (size_t)B_ * MAXF_ * (D_ / 4);  // 16,777,216
    lr_gather_kernel<<<(int)(n_vec4 / 256), 256, 0, stream>>>(
        (const float4*)x, idx_map, (float4*)out);
}

// Round 3
// 298.671 us; speedup vs baseline: 1.0338x; 1.0259x over previous
//
#include <hip/hip_runtime.h>
#include <hip/hip_bf16.h>

#define B_ 32
#define T_ 512
#define D_ 512
#define MAXF_ 4096

typedef float f4 __attribute__((ext_vector_type(4)));

// Stage 1: per-batch inclusive scan of durations in LDS, then direct scatter
// idx_map[start..end) = t (<=7 stores/thread) and -1 fill for masked tail.
__global__ __launch_bounds__(512) void lr_prep_kernel(const int* __restrict__ dur,
                                                      int* __restrict__ idx_map,
                                                      float* __restrict__ mel_out) {
    __shared__ int s[T_];
    const int b = blockIdx.x;
    const int t = threadIdx.x;
    const int d = dur[b * T_ + t];
    s[t] = d;
    __syncthreads();
    #pragma unroll
    for (int off = 1; off < T_; off <<= 1) {
        int tmp = (t >= off) ? s[t - off] : 0;
        __syncthreads();
        s[t] += tmp;
        __syncthreads();
    }
    const int end = s[t];
    const int start = end - d;
    const int total = s[T_ - 1];
    if (t == T_ - 1) {
        mel_out[b] = (float)(total > 1 ? total : 1);
    }
    int* __restrict__ im = idx_map + b * MAXF_;
    for (int p = start; p < end; ++p) im[p] = t;          // duration <= 7
    for (int p = total + t; p < MAXF_; p += T_) im[p] = -1;
}

// Stage 2: streaming gather. Each block owns a contiguous 2048-float4 chunk
// (16 consecutive frames -> x-row reuse stays in this CU's L1/L2).
// 8 independent unrolled iterations per thread; nontemporal stores keep the
// 256 MB output stream out of L2.
#define CHUNK_V4 2048
__global__ __launch_bounds__(256) void lr_gather_kernel(const f4* __restrict__ x,
                                                        const int* __restrict__ idx_map,
                                                        f4* __restrict__ out) {
    const size_t base = (size_t)blockIdx.x * CHUNK_V4 + threadIdx.x;
    #pragma unroll
    for (int k = 0; k < 8; ++k) {
        const size_t g = base + (size_t)k * 256;
        const int frame = (int)(g >> 7);     // b*MAXF_ + p
        const int c = (int)(g & 127);
        const int idx = idx_map[frame];
        f4 v = {0.f, 0.f, 0.f, 0.f};
        if (idx >= 0) {
            const int b = frame >> 12;       // MAXF_ = 4096
            v = x[((size_t)(b * T_ + idx) << 7) + c];
        }
        __builtin_nontemporal_store(v, &out[g]);
    }
}

extern "C" void kernel_launch(void* const* d_in, const int* in_sizes, int n_in,
                              void* d_out, int out_size, void* d_ws, size_t ws_size,
                              hipStream_t stream) {
    const float* x = (const float*)d_in[0];
    const int* durations = (const int*)d_in[1];
    float* out = (float*)d_out;
    float* mel_out = out + (size_t)B_ * MAXF_ * D_;
    int* idx_map = (int*)d_ws;  // B_*MAXF_ ints = 512 KB

    lr_prep_kernel<<<B_, T_, 0, stream>>>(durations, idx_map, mel_out);

    const size_t n_vec4 = (size_t)B_ * MAXF_ * (D_ / 4);  // 16,777,216
    lr_gather_kernel<<<(int)(n_vec4 / CHUNK_V4), 256, 0, stream>>>(
        (const f4*)x, idx_map, (f4*)out);
}